// Round 1
// baseline (418.296 us; speedup 1.0000x reference)
//
#include <hip/hip_runtime.h>
#include <cfloat>

#define DD 48
#define TT 512
#define BB 512

__device__ __forceinline__ float readlane_f(float v, int lane) {
  return __int_as_float(__builtin_amdgcn_readlane(__float_as_int(v), lane));
}

__global__ __launch_bounds__(64) void crf_viterbi(const float* __restrict__ logits,
                                                  const int* __restrict__ lens,
                                                  const float* __restrict__ trans,
                                                  int* __restrict__ out) {
  const int b = blockIdx.x;
  const int j = threadIdx.x;          // 0..63, lanes 0..47 are live tags
  const int jj = j < DD ? j : DD - 1; // clamp for safe global reads

  __shared__ unsigned char bp[TT * DD]; // backpointers, rows 1..L-1 used

  // Transition column j in registers (static-indexed after unroll -> VGPRs)
  float tcol[DD];
#pragma unroll
  for (int i = 0; i < DD; ++i) tcol[i] = trans[i * DD + jj];

  const float* lg = logits + (size_t)b * TT * DD;
  const int L = lens[b];

  float alpha = lg[jj]; // alpha0 = logits[b,0,:]

  // 2-deep emit prefetch
  float e0 = (L > 1) ? lg[DD + jj] : 0.f;
  float e1 = (L > 2) ? lg[2 * DD + jj] : 0.f;

  for (int t = 1; t < L; ++t) {
    float e = e0;
    e0 = e1;
    e1 = (t + 2 < L) ? lg[(t + 2) * DD + jj] : 0.f; // issue early, consume t+2

    // best_j = max_i(alpha[i] + trans[i][j]), argmax with first-index ties
    float best = readlane_f(alpha, 0) + tcol[0];
    int idx = 0;
#pragma unroll
    for (int i = 1; i < DD; ++i) {
      float s = readlane_f(alpha, i) + tcol[i];
      if (s > best) { best = s; idx = i; }
    }

    alpha = best + e;
    if (j < DD) bp[t * DD + j] = (unsigned char)idx;
  }

  __syncthreads(); // single wave: cheap; guarantees LDS writes visible

  // last_tag = argmax_j alpha (computed uniformly on all lanes)
  float bv = readlane_f(alpha, 0);
  int btag = 0;
#pragma unroll
  for (int i = 1; i < DD; ++i) {
    float v = readlane_f(alpha, i);
    if (v > bv) { bv = v; btag = i; }
  }

  int* ob = out + (size_t)b * TT;
  if (j == 0) ob[L - 1] = btag;

  // Backtrack by function composition:
  // H[j] = tag at current time given final tag j; one bpermute per step.
  int H = j;
  for (int t = L - 1; t >= 1; --t) {
    int v = bp[t * DD + jj];  // lane j reads bp_t[j] (independent of H -> pipelined)
    H = __shfl(v, H, 64);     // H' = bp_t[H]
    if (j == btag) ob[t - 1] = H;
  }

  // zero the padded tail t >= L
  for (int t = L + j; t < TT; t += 64) ob[t] = 0;
}

extern "C" void kernel_launch(void* const* d_in, const int* in_sizes, int n_in,
                              void* d_out, int out_size, void* d_ws, size_t ws_size,
                              hipStream_t stream) {
  const float* logits = (const float*)d_in[0];
  const int* lens     = (const int*)d_in[1];
  const float* trans  = (const float*)d_in[2];
  int* out            = (int*)d_out;
  (void)in_sizes; (void)n_in; (void)out_size; (void)d_ws; (void)ws_size;
  crf_viterbi<<<BB, 64, 0, stream>>>(logits, lens, trans, out);
}

// Round 2
// 362.416 us; speedup vs baseline: 1.1542x; 1.1542x over previous
//
#include <hip/hip_runtime.h>
#include <cfloat>

#define DD 48
#define TT 512
#define BB 512

__device__ __forceinline__ float readlane_f(float v, int lane) {
  return __int_as_float(__builtin_amdgcn_readlane(__float_as_int(v), lane));
}

// Tree max+argmax over s[0..47], first-index wins ties (strict > to move right).
__device__ __forceinline__ void tree_argmax48(const float* s, float& best, int& idx) {
  float v1[24]; int x1[24];
#pragma unroll
  for (int k = 0; k < 24; ++k) {
    bool g = s[2 * k + 1] > s[2 * k];
    v1[k] = g ? s[2 * k + 1] : s[2 * k];
    x1[k] = g ? 2 * k + 1 : 2 * k;
  }
  float v2[12]; int x2[12];
#pragma unroll
  for (int k = 0; k < 12; ++k) {
    bool g = v1[2 * k + 1] > v1[2 * k];
    v2[k] = g ? v1[2 * k + 1] : v1[2 * k];
    x2[k] = g ? x1[2 * k + 1] : x1[2 * k];
  }
  float v3[6]; int x3[6];
#pragma unroll
  for (int k = 0; k < 6; ++k) {
    bool g = v2[2 * k + 1] > v2[2 * k];
    v3[k] = g ? v2[2 * k + 1] : v2[2 * k];
    x3[k] = g ? x2[2 * k + 1] : x2[2 * k];
  }
  float v4[3]; int x4[3];
#pragma unroll
  for (int k = 0; k < 3; ++k) {
    bool g = v3[2 * k + 1] > v3[2 * k];
    v4[k] = g ? v3[2 * k + 1] : v3[2 * k];
    x4[k] = g ? x3[2 * k + 1] : x3[2 * k];
  }
  bool g0 = v4[1] > v4[0];
  float vm = g0 ? v4[1] : v4[0];
  int xm = g0 ? x4[1] : x4[0];
  bool g1 = v4[2] > vm;
  best = g1 ? v4[2] : vm;
  idx = g1 ? x4[2] : xm;
}

__global__ __launch_bounds__(64) void crf_viterbi(const float* __restrict__ logits,
                                                  const int* __restrict__ lens,
                                                  const float* __restrict__ trans,
                                                  int* __restrict__ out) {
  const int b = blockIdx.x;
  const int j = threadIdx.x;          // 0..63, lanes 0..47 are live tags
  const int jj = j < DD ? j : DD - 1; // clamp for safe global reads

  __shared__ unsigned char bp[TT * DD]; // backpointers, rows 1..L-1 used

  // Transition column j in registers (static-indexed after unroll -> VGPRs)
  float tcol[DD];
#pragma unroll
  for (int i = 0; i < DD; ++i) tcol[i] = trans[i * DD + jj];

  const float* lg = logits + (size_t)b * TT * DD;
  const int L = lens[b];

  float alpha = lg[jj]; // alpha0 = logits[b,0,:]

  // 2-deep emit prefetch
  float e0 = (L > 1) ? lg[DD + jj] : 0.f;
  float e1 = (L > 2) ? lg[2 * DD + jj] : 0.f;

  for (int t = 1; t < L; ++t) {
    float e = e0;
    e0 = e1;
    e1 = (t + 2 < L) ? lg[(t + 2) * DD + jj] : 0.f; // issue early, consume t+2

    // all 48 sums, independent (pipelined)
    float s[DD];
#pragma unroll
    for (int i = 0; i < DD; ++i) s[i] = readlane_f(alpha, i) + tcol[i];

    float best; int idx;
    tree_argmax48(s, best, idx);

    alpha = best + e;
    if (j < DD) bp[t * DD + j] = (unsigned char)idx;
  }

  __syncthreads(); // single wave: guarantees LDS writes visible

  // last_tag = argmax_j alpha (uniform on all lanes), same tree
  float af[DD];
#pragma unroll
  for (int i = 0; i < DD; ++i) af[i] = readlane_f(alpha, i);
  float bv; int btag;
  tree_argmax48(af, bv, btag);

  int* ob = out + (size_t)b * TT;
  if (j == 0) ob[L - 1] = btag;

  // Backtrack by function composition:
  // H[j] = tag at current time given final tag j; one bpermute per step.
  int H = j;
  for (int t = L - 1; t >= 1; --t) {
    int v = bp[t * DD + jj];  // lane j reads bp_t[j] (independent of H -> pipelined)
    H = __shfl(v, H, 64);     // H' = bp_t[H]
    if (j == btag) ob[t - 1] = H;
  }

  // zero the padded tail t >= L
  for (int t = L + j; t < TT; t += 64) ob[t] = 0;
}

extern "C" void kernel_launch(void* const* d_in, const int* in_sizes, int n_in,
                              void* d_out, int out_size, void* d_ws, size_t ws_size,
                              hipStream_t stream) {
  const float* logits = (const float*)d_in[0];
  const int* lens     = (const int*)d_in[1];
  const float* trans  = (const float*)d_in[2];
  int* out            = (int*)d_out;
  (void)in_sizes; (void)n_in; (void)out_size; (void)d_ws; (void)ws_size;
  crf_viterbi<<<BB, 64, 0, stream>>>(logits, lens, trans, out);
}

// Round 3
// 280.162 us; speedup vs baseline: 1.4931x; 1.2936x over previous
//
#include <hip/hip_runtime.h>

#define DD 48
#define TT 512
#define BB 512
#define STRIDE 64  // padded LDS row stride (unconditional 64-lane byte store)

__device__ __forceinline__ float readlane_f(float v, int lane) {
  return __int_as_float(__builtin_amdgcn_readlane(__float_as_int(v), lane));
}

// Tree max+argmax over s[0..47], first-index wins ties (strict > to move right).
__device__ __forceinline__ void tree_argmax48(const float* s, float& best, int& idx) {
  float v1[24]; int x1[24];
#pragma unroll
  for (int k = 0; k < 24; ++k) {
    bool g = s[2 * k + 1] > s[2 * k];
    v1[k] = g ? s[2 * k + 1] : s[2 * k];
    x1[k] = g ? 2 * k + 1 : 2 * k;
  }
  float v2[12]; int x2[12];
#pragma unroll
  for (int k = 0; k < 12; ++k) {
    bool g = v1[2 * k + 1] > v1[2 * k];
    v2[k] = g ? v1[2 * k + 1] : v1[2 * k];
    x2[k] = g ? x1[2 * k + 1] : x1[2 * k];
  }
  float v3[6]; int x3[6];
#pragma unroll
  for (int k = 0; k < 6; ++k) {
    bool g = v2[2 * k + 1] > v2[2 * k];
    v3[k] = g ? v2[2 * k + 1] : v2[2 * k];
    x3[k] = g ? x2[2 * k + 1] : x2[2 * k];
  }
  float v4[3]; int x4[3];
#pragma unroll
  for (int k = 0; k < 3; ++k) {
    bool g = v3[2 * k + 1] > v3[2 * k];
    v4[k] = g ? v3[2 * k + 1] : v3[2 * k];
    x4[k] = g ? x3[2 * k + 1] : x3[2 * k];
  }
  bool g0 = v4[1] > v4[0];
  float vm = g0 ? v4[1] : v4[0];
  int xm = g0 ? x4[1] : x4[0];
  bool g1 = v4[2] > vm;
  best = g1 ? v4[2] : vm;
  idx = g1 ? x4[2] : xm;
}

__global__ __launch_bounds__(64) void crf_viterbi(const float* __restrict__ logits,
                                                  const int* __restrict__ lens,
                                                  const float* __restrict__ trans,
                                                  int* __restrict__ out) {
  const int b = blockIdx.x;
  const int j = threadIdx.x;          // 0..63, lanes 0..47 are live tags
  const int jj = j < DD ? j : DD - 1; // clamp for safe global reads

  __shared__ unsigned char bp[TT * STRIDE]; // backpointers, rows 1..L-1 used

  // Transition column j in registers (static-indexed after unroll -> VGPRs)
  float tcol[DD];
#pragma unroll
  for (int i = 0; i < DD; ++i) tcol[i] = trans[i * DD + jj];

  const float* lg = logits + (size_t)b * TT * DD;
  const int L = lens[b];

  float alpha = lg[jj]; // alpha0 = logits[b,0,:]

  // 16-deep emit pipeline: two groups of 8 static slots.
  // eA[k] = row 1+k, eB[k] = row 9+k (rows always allocated: TT=512 per batch).
  float eA[8], eB[8];
#pragma unroll
  for (int k = 0; k < 8; ++k) {
    eA[k] = lg[(1 + k) * DD + jj];
    eB[k] = lg[(9 + k) * DD + jj];
  }

  // one Viterbi step consuming emit value e at time t (t uniform across wave)
  auto step = [&](int t, float e) {
    float s[DD];
#pragma unroll
    for (int i = 0; i < DD; ++i) s[i] = readlane_f(alpha, i) + tcol[i];
    float best; int idx;
    tree_argmax48(s, best, idx);
    alpha = best + e;
    bp[t * STRIDE + j] = (unsigned char)idx; // unconditional, padded stride
  };

  int t = 1;
  while (t < L) {
#pragma unroll
    for (int k = 0; k < 8; ++k) {       // consume group A (rows t..), reload +16
      if (t >= L) break;
      step(t, eA[k]);
      int r = t + 16; if (r > TT - 1) r = TT - 1;
      eA[k] = lg[r * DD + jj];          // unconditional, clamped: stays outstanding
      ++t;
    }
#pragma unroll
    for (int k = 0; k < 8; ++k) {       // consume group B, reload +16
      if (t >= L) break;
      step(t, eB[k]);
      int r = t + 16; if (r > TT - 1) r = TT - 1;
      eB[k] = lg[r * DD + jj];
      ++t;
    }
  }

  __syncthreads(); // single wave: guarantees LDS writes visible

  // last_tag = argmax_j alpha (uniform on all lanes), same tree
  float af[DD];
#pragma unroll
  for (int i = 0; i < DD; ++i) af[i] = readlane_f(alpha, i);
  float bv; int btag;
  tree_argmax48(af, bv, btag);

  int* ob = out + (size_t)b * TT;
  if (j == 0) ob[L - 1] = btag;

  // Backtrack by function composition:
  // H[j] = tag at current time given final tag j; one bpermute per step.
  int H = j;
  for (int tt = L - 1; tt >= 1; --tt) {
    int v = bp[tt * STRIDE + jj]; // addr independent of H -> pipelined
    H = __shfl(v, H, 64);         // H' = bp_t[H]
    if (j == btag) ob[tt - 1] = H;
  }

  // zero the padded tail t >= L
  for (int tt = L + j; tt < TT; tt += 64) ob[tt] = 0;
}

extern "C" void kernel_launch(void* const* d_in, const int* in_sizes, int n_in,
                              void* d_out, int out_size, void* d_ws, size_t ws_size,
                              hipStream_t stream) {
  const float* logits = (const float*)d_in[0];
  const int* lens     = (const int*)d_in[1];
  const float* trans  = (const float*)d_in[2];
  int* out            = (int*)d_out;
  (void)in_sizes; (void)n_in; (void)out_size; (void)d_ws; (void)ws_size;
  crf_viterbi<<<BB, 64, 0, stream>>>(logits, lens, trans, out);
}